// Round 1
// baseline (1128.829 us; speedup 1.0000x reference)
//
#include <hip/hip_runtime.h>

// Problem constants
#define Bdim 2048
#define Sdim 32
#define Ddim 1024
#define Fdim 512
#define Hdim 512

typedef __bf16 bf16_t;
typedef __bf16 bf16x8 __attribute__((ext_vector_type(8)));
typedef __bf16 bf16x4 __attribute__((ext_vector_type(4)));
typedef float  f32x4  __attribute__((ext_vector_type(4)));

#define BM 128
#define BN 128
#define BK 32

// ---------------- async global->LDS, 16B per lane ----------------
__device__ __forceinline__ void gll16(const bf16_t* g, bf16_t* l) {
  __builtin_amdgcn_global_load_lds((const __attribute__((address_space(1))) void*)g,
                                   (__attribute__((address_space(3))) void*)l,
                                   16, 0, 0);
}

// ---------------- fp32 -> bf16 convert ----------------
__global__ void k_cvt(const float* __restrict__ s, bf16_t* __restrict__ d, long n) {
  long i = ((long)blockIdx.x * blockDim.x + threadIdx.x) * 4;
  long stride = (long)gridDim.x * blockDim.x * 4;
  for (; i < n; i += stride) {
    float4 v = *(const float4*)(s + i);
    bf16x4 o;
    o[0] = (bf16_t)v.x; o[1] = (bf16_t)v.y; o[2] = (bf16_t)v.z; o[3] = (bf16_t)v.w;
    *(bf16x4*)(d + i) = o;
  }
}

// ---------------- bias precompute: u = Wq^T bk, w = Wk^T bq, b' = Wo bv + out_b, c0 = bq.bk
__global__ void k_bias_pre(const float* __restrict__ ipw, const float* __restrict__ ipb,
                           const float* __restrict__ ow, const float* __restrict__ ob,
                           float* __restrict__ u, float* __restrict__ w,
                           float* __restrict__ bp, float* __restrict__ c0) {
  int blk = blockIdx.x, tid = threadIdx.x;
  if (blk < 4) {
    int d = blk * 256 + tid;
    float acc = 0.f;
    for (int e = 0; e < Ddim; ++e) acc += ipw[(long)e * Ddim + d] * ipb[Ddim + e];
    u[d] = acc;
  } else if (blk < 8) {
    int d = (blk - 4) * 256 + tid;
    float acc = 0.f;
    for (int e = 0; e < Ddim; ++e) acc += ipw[(long)(Ddim + e) * Ddim + d] * ipb[e];
    w[d] = acc;
  } else if (blk < 136) {
    int o = (blk - 8) * 8 + (tid >> 5);
    int l = tid & 31;
    float acc = 0.f;
    for (int e = l; e < Ddim; e += 32) acc += ow[(long)o * Ddim + e] * ipb[2 * Ddim + e];
    #pragma unroll
    for (int m = 1; m < 32; m <<= 1) acc += __shfl_xor(acc, m);
    if (l == 0) bp[o] = acc + ob[o];
  } else {
    __shared__ float red[256];
    float acc = 0.f;
    for (int e = tid; e < Ddim; e += 256) acc += ipb[e] * ipb[Ddim + e];
    red[tid] = acc;
    __syncthreads();
    for (int off = 128; off; off >>= 1) {
      if (tid < off) red[tid] += red[tid + off];
      __syncthreads();
    }
    if (tid == 0) c0[0] = red[0];
  }
}

// ---------------- generic 128x128x32 MFMA mainloop ----------------
// C[m,n] = sum_k A[m,k] * B[k,n]
// AT==0: A row-major (M x K). AT==1: A stored row-major (K x M) (transposed-staged).
// BT==0: B given as Bt row-major (N x K). BT==1: B row-major (K x N) (transposed-staged).
template<int AT, int BT>
__device__ __forceinline__ void gemm_tile(const bf16_t* __restrict__ A, long lda,
                                          const bf16_t* __restrict__ Bt, long ldb,
                                          long m0, long n0, int K,
                                          bf16_t* sa, bf16_t* sb, f32x4 acc[4][4]) {
  const int tid  = threadIdx.x;
  const int wave = tid >> 6;
  const int lane = tid & 63;
  const int quad = lane >> 4;
  const int l16  = lane & 15;
  const int wm = (wave & 1) * 64;
  const int wn = (wave >> 1) * 64;

  for (int kt = 0; kt < K; kt += BK) {
    __syncthreads();
    if constexpr (AT == 0) {
      #pragma unroll
      for (int r = 0; r < 2; ++r) {
        int L = r * 256 + tid;
        const bf16_t* g = A + (m0 + (L >> 2)) * lda + kt + (L & 3) * 8;
        gll16(g, sa + (long)(r * 256 + wave * 64) * 8);
      }
    } else {
      #pragma unroll
      for (int r = 0; r < 2; ++r) {
        int L = r * 256 + tid;
        int gk = L >> 4, gm = (L & 15) * 8;
        bf16x8 v = *(const bf16x8*)(A + (long)(kt + gk) * lda + m0 + gm);
        #pragma unroll
        for (int j = 0; j < 8; ++j) sa[(gm + j) * BK + gk] = v[j];
      }
    }
    if constexpr (BT == 0) {
      #pragma unroll
      for (int r = 0; r < 2; ++r) {
        int L = r * 256 + tid;
        const bf16_t* g = Bt + (n0 + (L >> 2)) * ldb + kt + (L & 3) * 8;
        gll16(g, sb + (long)(r * 256 + wave * 64) * 8);
      }
    } else {
      #pragma unroll
      for (int r = 0; r < 2; ++r) {
        int L = r * 256 + tid;
        int gk = L >> 4, gn = (L & 15) * 8;
        bf16x8 v = *(const bf16x8*)(Bt + (long)(kt + gk) * ldb + n0 + gn);
        #pragma unroll
        for (int j = 0; j < 8; ++j) sb[(gn + j) * BK + gk] = v[j];
      }
    }
    __syncthreads();
    bf16x8 af[4], bfr[4];
    #pragma unroll
    for (int i = 0; i < 4; ++i)
      af[i] = *(const bf16x8*)(sa + (wm + i * 16 + l16) * BK + quad * 8);
    #pragma unroll
    for (int j = 0; j < 4; ++j)
      bfr[j] = *(const bf16x8*)(sb + (wn + j * 16 + l16) * BK + quad * 8);
    #pragma unroll
    for (int i = 0; i < 4; ++i)
      #pragma unroll
      for (int j = 0; j < 4; ++j)
        acc[i][j] = __builtin_amdgcn_mfma_f32_16x16x32_bf16(af[i], bfr[j], acc[i][j], 0, 0, 0);
  }
}

// ---------------- GEMM with bf16 output (+optional fp32 bias on n) ----------------
template<int AT, int BT>
__global__ __launch_bounds__(256) void k_gemm_bf16(
    const bf16_t* __restrict__ A, long lda, long sAz,
    const bf16_t* __restrict__ Bt, long ldb, long sBz,
    bf16_t* __restrict__ C, long ldc, long sCz,
    const float* __restrict__ bias, int K) {
  __shared__ bf16_t sa[BM * BK];
  __shared__ bf16_t sb[BN * BK];
  long n0 = (long)blockIdx.x * BN;
  long m0 = (long)blockIdx.y * BM;
  long z  = blockIdx.z;
  const bf16_t* Az = A + z * sAz;
  const bf16_t* Bz = Bt + z * sBz;
  bf16_t* Cz = C + z * sCz;
  f32x4 acc[4][4];
  #pragma unroll
  for (int i = 0; i < 4; ++i)
    #pragma unroll
    for (int j = 0; j < 4; ++j) acc[i][j] = (f32x4){0.f, 0.f, 0.f, 0.f};
  gemm_tile<AT, BT>(Az, lda, Bz, ldb, m0, n0, K, sa, sb, acc);
  const int tid = threadIdx.x, wave = tid >> 6, lane = tid & 63;
  const int quad = lane >> 4, l16 = lane & 15;
  const int wm = (wave & 1) * 64, wn = (wave >> 1) * 64;
  #pragma unroll
  for (int j = 0; j < 4; ++j) {
    long col = n0 + wn + j * 16 + l16;
    float bv = bias ? bias[col] : 0.f;
    #pragma unroll
    for (int i = 0; i < 4; ++i)
      #pragma unroll
      for (int r = 0; r < 4; ++r) {
        long row = m0 + wm + i * 16 + quad * 4 + r;
        Cz[row * ldc + col] = (bf16_t)(acc[i][j][r] + bv);
      }
  }
}

// ---------------- GEMM with fp32 output (heads) ----------------
__global__ __launch_bounds__(256) void k_gemm_f32(
    const bf16_t* __restrict__ A, long lda, long sAz,
    const bf16_t* __restrict__ Bt, long ldb, long sBz,
    float* __restrict__ C, long ldc, long sCz, int K) {
  __shared__ bf16_t sa[BM * BK];
  __shared__ bf16_t sb[BN * BK];
  long n0 = (long)blockIdx.x * BN;
  long m0 = (long)blockIdx.y * BM;
  long z  = blockIdx.z;
  const bf16_t* Az = A + z * sAz;
  const bf16_t* Bz = Bt + z * sBz;
  float* Cz = C + z * sCz;
  f32x4 acc[4][4];
  #pragma unroll
  for (int i = 0; i < 4; ++i)
    #pragma unroll
    for (int j = 0; j < 4; ++j) acc[i][j] = (f32x4){0.f, 0.f, 0.f, 0.f};
  gemm_tile<0, 0>(Az, lda, Bz, ldb, m0, n0, K, sa, sb, acc);
  const int tid = threadIdx.x, wave = tid >> 6, lane = tid & 63;
  const int quad = lane >> 4, l16 = lane & 15;
  const int wm = (wave & 1) * 64, wn = (wave >> 1) * 64;
  #pragma unroll
  for (int j = 0; j < 4; ++j) {
    long col = n0 + wn + j * 16 + l16;
    #pragma unroll
    for (int i = 0; i < 4; ++i)
      #pragma unroll
      for (int r = 0; r < 4; ++r) {
        long row = m0 + wm + i * 16 + quad * 4 + r;
        Cz[row * ldc + col] = acc[i][j][r];
      }
  }
}

// ---------------- classifier GEMM: h=relu(q@w1^T+b1); partial d = sum relu(h)*w2 -> atomic
__global__ __launch_bounds__(256) void k_gemm_cls(
    const bf16_t* __restrict__ q16, const bf16_t* __restrict__ w1,
    const float* __restrict__ b1, const float* __restrict__ w2,
    float* __restrict__ dsum) {
  __shared__ bf16_t sa[BM * BK];
  __shared__ bf16_t sb[BN * BK];
  int s = blockIdx.z;
  long n0 = (long)blockIdx.x * BN;
  long m0 = (long)blockIdx.y * BM;
  const bf16_t* A  = q16 + (long)s * Ddim;                 // row b stride S*D
  const bf16_t* Bt = w1 + (long)s * Hdim * Ddim;
  f32x4 acc[4][4];
  #pragma unroll
  for (int i = 0; i < 4; ++i)
    #pragma unroll
    for (int j = 0; j < 4; ++j) acc[i][j] = (f32x4){0.f, 0.f, 0.f, 0.f};
  gemm_tile<0, 0>(A, (long)Sdim * Ddim, Bt, Ddim, m0, n0, Ddim, sa, sb, acc);
  const int tid = threadIdx.x, wave = tid >> 6, lane = tid & 63;
  const int quad = lane >> 4, l16 = lane & 15;
  const int wm = (wave & 1) * 64, wn = (wave >> 1) * 64;
  float b1v[4], w2v[4];
  #pragma unroll
  for (int j = 0; j < 4; ++j) {
    long col = n0 + wn + j * 16 + l16;
    b1v[j] = b1[(long)s * Hdim + col];
    w2v[j] = w2[(long)s * Hdim + col];
  }
  #pragma unroll
  for (int i = 0; i < 4; ++i)
    #pragma unroll
    for (int r = 0; r < 4; ++r) {
      float v = 0.f;
      #pragma unroll
      for (int j = 0; j < 4; ++j) v += fmaxf(acc[i][j][r] + b1v[j], 0.f) * w2v[j];
      v += __shfl_xor(v, 1);
      v += __shfl_xor(v, 2);
      v += __shfl_xor(v, 4);
      v += __shfl_xor(v, 8);
      if (l16 == 0) {
        long row = m0 + wm + i * 16 + quad * 4 + r;
        atomicAdd(&dsum[row * Sdim + s], v);
      }
    }
}

// ---------------- d finalize: relu + two 16-way softmaxes ----------------
__global__ void k_finalize_d(const float* __restrict__ dsum, const float* __restrict__ cb2,
                             float* __restrict__ daws, float* __restrict__ out_da,
                             float* __restrict__ out_dv) {
  int t = blockIdx.x * 256 + threadIdx.x;   // over B*S
  int b = t >> 5, s = t & 31;
  float v = fmaxf(dsum[t] + cb2[s], 0.f);
  float m = v;
  #pragma unroll
  for (int mask = 1; mask < 16; mask <<= 1) m = fmaxf(m, __shfl_xor(m, mask));
  float e = __expf(v - m);
  float sum = e;
  #pragma unroll
  for (int mask = 1; mask < 16; mask <<= 1) sum += __shfl_xor(sum, mask);
  float r = e / sum;
  daws[t] = r;
  if (s < 16) out_da[b * 16 + s] = r;
  else        out_dv[b * 16 + (s - 16)] = r;
}

// ---------------- per-batch: scores -> softmax -> pool weights -> pooled vectors ----------------
#define QPAD 264
__global__ __launch_bounds__(256) void k_attn_pool(
    const bf16_t* __restrict__ q16, const bf16_t* __restrict__ G16,
    const float* __restrict__ daws, const float* __restrict__ u,
    const float* __restrict__ wv, const float* __restrict__ c0p,
    bf16_t* __restrict__ pooled) {
  __shared__ bf16_t qc[32 * QPAD];
  __shared__ bf16_t gc[32 * QPAD];
  __shared__ float sc[32][33];
  __shared__ float qup[32][8], qwp[32][8];
  __shared__ float quL[32], qwL[32], caL[32], cvL[32], daL[16], dvL[16];
  const int tid = threadIdx.x, wave = tid >> 6, lane = tid & 63;
  const int quad = lane >> 4, l16 = lane & 15;
  const long b = blockIdx.x;
  const bf16_t* qb = q16 + b * (Sdim * Ddim);
  const bf16_t* gb = G16 + b * (Sdim * Ddim);
  if (tid < 32) {
    float dval = daws[b * Sdim + tid];
    if (tid < 16) daL[tid] = dval; else dvL[tid - 16] = dval;
  }
  qup[tid >> 3][tid & 7] = 0.f;
  qwp[tid >> 3][tid & 7] = 0.f;
  const int ti = wave & 1, tj = wave >> 1;
  f32x4 acc = (f32x4){0.f, 0.f, 0.f, 0.f};
  for (int kc = 0; kc < Ddim; kc += 256) {
    __syncthreads();
    #pragma unroll
    for (int r = 0; r < 4; ++r) {
      int L = r * 256 + tid;
      int row = L >> 5, koff = (L & 31) * 8;
      *(bf16x8*)(qc + row * QPAD + koff) = *(const bf16x8*)(qb + (long)row * Ddim + kc + koff);
      *(bf16x8*)(gc + row * QPAD + koff) = *(const bf16x8*)(gb + (long)row * Ddim + kc + koff);
    }
    __syncthreads();
    #pragma unroll
    for (int kk = 0; kk < 8; ++kk) {
      bf16x8 a  = *(const bf16x8*)(gc + (ti * 16 + l16) * QPAD + kk * 32 + quad * 8);
      bf16x8 bb = *(const bf16x8*)(qc + (tj * 16 + l16) * QPAD + kk * 32 + quad * 8);
      acc = __builtin_amdgcn_mfma_f32_16x16x32_bf16(a, bb, acc, 0, 0, 0);
    }
    {
      int s2 = tid & 31, sl = tid >> 5;
      float pu = 0.f, pw = 0.f;
      const bf16_t* qrow = qc + s2 * QPAD + sl * 32;
      for (int k = 0; k < 32; ++k) {
        float qv = (float)qrow[k];
        pu += qv * u[kc + sl * 32 + k];
        pw += qv * wv[kc + sl * 32 + k];
      }
      qup[s2][sl] += pu;
      qwp[s2][sl] += pw;
    }
  }
  __syncthreads();
  if (tid < 32) {
    float a0 = 0.f, a1 = 0.f;
    for (int k = 0; k < 8; ++k) { a0 += qup[tid][k]; a1 += qwp[tid][k]; }
    quL[tid] = a0; qwL[tid] = a1;
  }
  __syncthreads();
  {
    float c00 = c0p[0];
    int col = tj * 16 + l16;
    #pragma unroll
    for (int r = 0; r < 4; ++r) {
      int row = ti * 16 + quad * 4 + r;
      sc[row][col] = (acc[r] + quL[row] + qwL[col] + c00) * 0.03125f;
    }
  }
  __syncthreads();
  if (tid < 32) {
    float mx = -1e30f;
    for (int t = 0; t < 32; ++t) mx = fmaxf(mx, sc[tid][t]);
    float sum = 0.f;
    for (int t = 0; t < 32; ++t) { float e = __expf(sc[tid][t] - mx); sc[tid][t] = e; sum += e; }
    float inv = 1.f / sum;
    for (int t = 0; t < 32; ++t) sc[tid][t] *= inv;
  }
  __syncthreads();
  if (tid < 32) {
    float a0 = 0.f, a1 = 0.f;
    for (int s2 = 0; s2 < 16; ++s2) a0 += daL[s2] * sc[s2][tid];
    for (int s2 = 0; s2 < 16; ++s2) a1 += dvL[s2] * sc[16 + s2][tid];
    caL[tid] = a0; cvL[tid] = a1;
  }
  __syncthreads();
  for (int d = tid; d < Ddim; d += 256) {
    float ap = 0.f, vp = 0.f;
    for (int t = 0; t < 32; ++t) {
      float qv = (float)qb[(long)t * Ddim + d];
      ap += caL[t] * qv;
      vp += cvL[t] * qv;
    }
    pooled[b * 3072 + d]        = (bf16_t)(0.5f * (ap + vp));
    pooled[b * 3072 + 1024 + d] = (bf16_t)ap;
    pooled[b * 3072 + 2048 + d] = (bf16_t)vp;
  }
}

// ---------------- LayerNorm + ReLU over F=512 (one wave per row) ----------------
__global__ __launch_bounds__(256) void k_ln(
    const float* __restrict__ Y,
    const float* __restrict__ fb, const float* __restrict__ fg, const float* __restrict__ fbe,
    const float* __restrict__ ab, const float* __restrict__ ag, const float* __restrict__ abe,
    const float* __restrict__ vb, const float* __restrict__ vg, const float* __restrict__ vbe,
    float* __restrict__ out) {
  int wave = threadIdx.x >> 6, lane = threadIdx.x & 63;
  long row = (long)blockIdx.x * 4 + wave;        // [0, 3*B)
  int head = (int)(row >> 11);
  const float* bb = (head == 0) ? fb : (head == 1) ? ab : vb;
  const float* gg = (head == 0) ? fg : (head == 1) ? ag : vg;
  const float* be = (head == 0) ? fbe : (head == 1) ? abe : vbe;
  const float* y = Y + row * Fdim + lane * 8;
  float v[8];
  float s = 0.f;
  #pragma unroll
  for (int k = 0; k < 8; ++k) { v[k] = y[k] + bb[lane * 8 + k]; s += v[k]; }
  #pragma unroll
  for (int m = 1; m < 64; m <<= 1) s += __shfl_xor(s, m);
  float mu = s * (1.f / Fdim);
  float vs = 0.f;
  #pragma unroll
  for (int k = 0; k < 8; ++k) { float t = v[k] - mu; vs += t * t; }
  #pragma unroll
  for (int m = 1; m < 64; m <<= 1) vs += __shfl_xor(vs, m);
  float inv = rsqrtf(vs * (1.f / Fdim) + 1e-5f);
  float* o = out + row * Fdim + lane * 8;
  #pragma unroll
  for (int k = 0; k < 8; ++k) {
    float t = (v[k] - mu) * inv * gg[lane * 8 + k] + be[lane * 8 + k];
    o[k] = fmaxf(t, 0.f);
  }
}

// ---------------- launch ----------------
extern "C" void kernel_launch(void* const* d_in, const int* in_sizes, int n_in,
                              void* d_out, int out_size, void* d_ws, size_t ws_size,
                              hipStream_t stream) {
  const float* q    = (const float*)d_in[0];
  const float* ipw  = (const float*)d_in[1];
  const float* ipb  = (const float*)d_in[2];
  const float* ow   = (const float*)d_in[3];
  const float* ob   = (const float*)d_in[4];
  const float* cw1  = (const float*)d_in[5];
  const float* cb1  = (const float*)d_in[6];
  const float* cw2  = (const float*)d_in[7];
  const float* cb2  = (const float*)d_in[8];
  const float* fusw = (const float*)d_in[9];
  const float* fusb = (const float*)d_in[10];
  const float* fusg = (const float*)d_in[11];
  const float* fusbe= (const float*)d_in[12];
  const float* paw  = (const float*)d_in[13];
  const float* pab  = (const float*)d_in[14];
  const float* pag  = (const float*)d_in[15];
  const float* pabe = (const float*)d_in[16];
  const float* pvw  = (const float*)d_in[17];
  const float* pvb  = (const float*)d_in[18];
  const float* pvg  = (const float*)d_in[19];
  const float* pvbe = (const float*)d_in[20];
  float* out = (float*)d_out;

  // workspace layout (bytes)
  const size_t o_q16   = 0;                    // 134217728
  const size_t o_w16   = 134217728;            // 6291456 (Wq,Wk,Wv)
  const size_t o_ow16  = 140509184;            // 2097152
  const size_t o_cls16 = 142606336;            // 33554432
  const size_t o_hw16  = 176160768;            // 3145728 (fus,pa,pv)
  const size_t o_Mt    = 179306496;            // 2097152
  const size_t o_Nt    = 181403648;            // 2097152
  const size_t o_G16   = 183500800;            // 134217728 (aliased later by S1,Y)
  const size_t o_pool  = 317718528;            // 12582912
  const size_t o_u     = 330301440;            // 4096
  const size_t o_wv    = 330305536;            // 4096
  const size_t o_bp    = 330309632;            // 4096
  const size_t o_c0    = 330313728;            // 256
  const size_t o_dsum  = 330313984;            // 262144
  const size_t o_daws  = 330576128;            // 262144
  const size_t total   = 330838272;
  if (ws_size < total) return;  // workspace too small -> clean fail, diagnose next round

  char* ws = (char*)d_ws;
  bf16_t* q16   = (bf16_t*)(ws + o_q16);
  bf16_t* w16   = (bf16_t*)(ws + o_w16);
  bf16_t* Wq16  = w16;
  bf16_t* Wk16  = w16 + 1048576;
  bf16_t* Wv16  = w16 + 2097152;
  bf16_t* ow16  = (bf16_t*)(ws + o_ow16);
  bf16_t* cls16 = (bf16_t*)(ws + o_cls16);
  bf16_t* hw16  = (bf16_t*)(ws + o_hw16);
  bf16_t* Mt    = (bf16_t*)(ws + o_Mt);
  bf16_t* Nt    = (bf16_t*)(ws + o_Nt);
  bf16_t* G16   = (bf16_t*)(ws + o_G16);
  bf16_t* S116  = (bf16_t*)(ws + o_G16);                 // alias (G16 dead by then)
  float*  Yf    = (float*)(ws + o_G16 + 12582912);       // alias
  bf16_t* pool16= (bf16_t*)(ws + o_pool);
  float*  uf    = (float*)(ws + o_u);
  float*  wvf   = (float*)(ws + o_wv);
  float*  bpf   = (float*)(ws + o_bp);
  float*  c0f   = (float*)(ws + o_c0);
  float*  dsum  = (float*)(ws + o_dsum);
  float*  daws  = (float*)(ws + o_daws);

  auto cvt = [&](const float* s, bf16_t* d, long n) {
    long blocks = (n / 4 + 255) / 256;
    if (blocks > 8192) blocks = 8192;
    k_cvt<<<dim3((unsigned)blocks), dim3(256), 0, stream>>>(s, d, n);
  };

  // 1) converts
  cvt(q,    q16,   (long)Bdim * Sdim * Ddim);
  cvt(ipw,  w16,   3L * Ddim * Ddim);
  cvt(ow,   ow16,  (long)Ddim * Ddim);
  cvt(cw1,  cls16, (long)Sdim * Hdim * Ddim);
  cvt(fusw, hw16,            (long)Fdim * Ddim);
  cvt(paw,  hw16 + 524288,   (long)Fdim * Ddim);
  cvt(pvw,  hw16 + 1048576,  (long)Fdim * Ddim);

  // 2) bias precompute
  k_bias_pre<<<dim3(137), dim3(256), 0, stream>>>(ipw, ipb, ow, ob, uf, wvf, bpf, c0f);

  // 3) M^T = Wk^T Wq  (A = Wk stored KxM -> AT=1; B = Wq stored KxN -> BT=1)
  k_gemm_bf16<1, 1><<<dim3(8, 8, 1), dim3(256), 0, stream>>>(
      Wk16, Ddim, 0, Wq16, Ddim, 0, Mt, Ddim, 0, nullptr, Ddim);

  // 4) N^T = Wo @ Wv  (A = out_w row-major MxK; B = Wv stored KxN -> BT=1)
  k_gemm_bf16<0, 1><<<dim3(8, 8, 1), dim3(256), 0, stream>>>(
      ow16, Ddim, 0, Wv16, Ddim, 0, Nt, Ddim, 0, nullptr, Ddim);

  // 5) G = q16 @ M   (Bt = M^T)
  k_gemm_bf16<0, 0><<<dim3(8, 512, 1), dim3(256), 0, stream>>>(
      q16, Ddim, 0, Mt, Ddim, 0, G16, Ddim, 0, nullptr, Ddim);

  // 6) classifier: dsum[b,s] = sum_j relu(q.w1^T + b1)*w2
  hipMemsetAsync(dsum, 0, (size_t)Bdim * Sdim * sizeof(float), stream);
  k_gemm_cls<<<dim3(4, 16, 32), dim3(256), 0, stream>>>(q16, cls16, cb1, cw2, dsum);

  // 7) d -> softmaxes -> d_a,d_v outputs + ws copy
  k_finalize_d<<<dim3(256), dim3(256), 0, stream>>>(
      dsum, cb2, daws, out + 3145728, out + 3145728 + 32768);

  // 8) per-batch attention scores + pooling
  k_attn_pool<<<dim3(2048), dim3(256), 0, stream>>>(q16, G16, daws, uf, wvf, c0f, pool16);

  // 9) S1 = pooled @ N + b'  (rows: b*3 + {fus,audio,video})
  k_gemm_bf16<0, 0><<<dim3(8, 48, 1), dim3(256), 0, stream>>>(
      pool16, Ddim, 0, Nt, Ddim, 0, S116, Ddim, 0, bpf, Ddim);

  // 10) heads: Y[z] = S1[:,z,:] @ headw[z]^T  (z = fusion, audio, video)
  k_gemm_f32<<<dim3(4, 16, 3), dim3(256), 0, stream>>>(
      S116, 3L * Ddim, Ddim, hw16, Ddim, (long)Fdim * Ddim,
      Yf, Fdim, (long)Bdim * Fdim, Ddim);

  // 11) LN + ReLU -> out
  k_ln<<<dim3(1536), dim3(256), 0, stream>>>(
      Yf, fusb, fusg, fusbe, pab, pag, pabe, pvb, pvg, pvbe, out);
}

// Round 2
// 1058.145 us; speedup vs baseline: 1.0668x; 1.0668x over previous
//
#include <hip/hip_runtime.h>

// Problem constants
#define Bdim 2048
#define Sdim 32
#define Ddim 1024
#define Fdim 512
#define Hdim 512

typedef __bf16 bf16_t;
typedef __bf16 bf16x8 __attribute__((ext_vector_type(8)));
typedef __bf16 bf16x4 __attribute__((ext_vector_type(4)));
typedef float  f32x4  __attribute__((ext_vector_type(4)));

#define BM 128
#define BN 128
#define BK 32

// ---------------- async global->LDS, 16B per lane ----------------
__device__ __forceinline__ void gll16(const bf16_t* g, bf16_t* l) {
  __builtin_amdgcn_global_load_lds((const __attribute__((address_space(1))) void*)g,
                                   (__attribute__((address_space(3))) void*)l,
                                   16, 0, 0);
}

// ---------------- fused fp32 -> bf16 convert for ALL weight/input tensors ----------------
// virtual float4-index space, compile-time segment boundaries
__global__ void k_cvt_all(const float* __restrict__ q, const float* __restrict__ ipw,
                          const float* __restrict__ ow, const float* __restrict__ cw1,
                          const float* __restrict__ fusw, const float* __restrict__ paw,
                          const float* __restrict__ pvw,
                          bf16_t* __restrict__ q16, bf16_t* __restrict__ w16,
                          bf16_t* __restrict__ ow16, bf16_t* __restrict__ cls16,
                          bf16_t* __restrict__ hw16) {
  long v = (long)blockIdx.x * 256 + threadIdx.x;
  const float* s; bf16_t* d; long off;
  if (v < 16777216L)      { s = q;    d = q16;            off = 0; }
  else if (v < 17563648L) { s = ipw;  d = w16;            off = 16777216L; }
  else if (v < 17825792L) { s = ow;   d = ow16;           off = 17563648L; }
  else if (v < 22020096L) { s = cw1;  d = cls16;          off = 17825792L; }
  else if (v < 22151168L) { s = fusw; d = hw16;           off = 22020096L; }
  else if (v < 22282240L) { s = paw;  d = hw16 + 524288;  off = 22151168L; }
  else                    { s = pvw;  d = hw16 + 1048576; off = 22282240L; }
  long i = (v - off) * 4;
  float4 t = *(const float4*)(s + i);
  bf16x4 o;
  o[0] = (bf16_t)t.x; o[1] = (bf16_t)t.y; o[2] = (bf16_t)t.z; o[3] = (bf16_t)t.w;
  *(bf16x4*)(d + i) = o;
}

// ---------------- bias precompute: u = Wq^T bk, w = Wk^T bq, b' = Wo bv + out_b, c0 = bq.bk
__global__ void k_bias_pre(const float* __restrict__ ipw, const float* __restrict__ ipb,
                           const float* __restrict__ ow, const float* __restrict__ ob,
                           float* __restrict__ u, float* __restrict__ w,
                           float* __restrict__ bp, float* __restrict__ c0) {
  int blk = blockIdx.x, tid = threadIdx.x;
  if (blk < 4) {
    int d = blk * 256 + tid;
    float acc = 0.f;
    for (int e = 0; e < Ddim; ++e) acc += ipw[(long)e * Ddim + d] * ipb[Ddim + e];
    u[d] = acc;
  } else if (blk < 8) {
    int d = (blk - 4) * 256 + tid;
    float acc = 0.f;
    for (int e = 0; e < Ddim; ++e) acc += ipw[(long)(Ddim + e) * Ddim + d] * ipb[e];
    w[d] = acc;
  } else if (blk < 136) {
    int o = (blk - 8) * 8 + (tid >> 5);
    int l = tid & 31;
    float acc = 0.f;
    for (int e = l; e < Ddim; e += 32) acc += ow[(long)o * Ddim + e] * ipb[2 * Ddim + e];
    #pragma unroll
    for (int m = 1; m < 32; m <<= 1) acc += __shfl_xor(acc, m);
    if (l == 0) bp[o] = acc + ob[o];
  } else {
    __shared__ float red[256];
    float acc = 0.f;
    for (int e = tid; e < Ddim; e += 256) acc += ipb[e] * ipb[Ddim + e];
    red[tid] = acc;
    __syncthreads();
    for (int off = 128; off; off >>= 1) {
      if (tid < off) red[tid] += red[tid + off];
      __syncthreads();
    }
    if (tid == 0) c0[0] = red[0];
  }
}

// ---------------- generic 128x128x32 MFMA mainloop (operand-swapped mfma) ----------------
// After the swap, acc[i][j][r] = C[m0+wm+i*16+l16][n0+wn+j*16+quad*4+r]
template<int AT, int BT>
__device__ __forceinline__ void gemm_tile(const bf16_t* __restrict__ A, long lda,
                                          const bf16_t* __restrict__ Bt, long ldb,
                                          long m0, long n0, int K,
                                          bf16_t* sa, bf16_t* sb, f32x4 acc[4][4]) {
  const int tid  = threadIdx.x;
  const int wave = tid >> 6;
  const int lane = tid & 63;
  const int quad = lane >> 4;
  const int l16  = lane & 15;
  const int wm = (wave & 1) * 64;
  const int wn = (wave >> 1) * 64;

  for (int kt = 0; kt < K; kt += BK) {
    __syncthreads();
    if constexpr (AT == 0) {
      #pragma unroll
      for (int r = 0; r < 2; ++r) {
        int L = r * 256 + tid;
        const bf16_t* g = A + (m0 + (L >> 2)) * lda + kt + (L & 3) * 8;
        gll16(g, sa + (long)(r * 256 + wave * 64) * 8);
      }
    } else {
      #pragma unroll
      for (int r = 0; r < 2; ++r) {
        int L = r * 256 + tid;
        int gk = L >> 4, gm = (L & 15) * 8;
        bf16x8 v = *(const bf16x8*)(A + (long)(kt + gk) * lda + m0 + gm);
        #pragma unroll
        for (int j = 0; j < 8; ++j) sa[(gm + j) * BK + gk] = v[j];
      }
    }
    if constexpr (BT == 0) {
      #pragma unroll
      for (int r = 0; r < 2; ++r) {
        int L = r * 256 + tid;
        const bf16_t* g = Bt + (n0 + (L >> 2)) * ldb + kt + (L & 3) * 8;
        gll16(g, sb + (long)(r * 256 + wave * 64) * 8);
      }
    } else {
      #pragma unroll
      for (int r = 0; r < 2; ++r) {
        int L = r * 256 + tid;
        int gk = L >> 4, gn = (L & 15) * 8;
        bf16x8 v = *(const bf16x8*)(Bt + (long)(kt + gk) * ldb + n0 + gn);
        #pragma unroll
        for (int j = 0; j < 8; ++j) sb[(gn + j) * BK + gk] = v[j];
      }
    }
    __syncthreads();
    bf16x8 af[4], bfr[4];
    #pragma unroll
    for (int i = 0; i < 4; ++i)
      af[i] = *(const bf16x8*)(sa + (wm + i * 16 + l16) * BK + quad * 8);
    #pragma unroll
    for (int j = 0; j < 4; ++j)
      bfr[j] = *(const bf16x8*)(sb + (wn + j * 16 + l16) * BK + quad * 8);
    #pragma unroll
    for (int i = 0; i < 4; ++i)
      #pragma unroll
      for (int j = 0; j < 4; ++j)
        acc[i][j] = __builtin_amdgcn_mfma_f32_16x16x32_bf16(bfr[j], af[i], acc[i][j], 0, 0, 0);
  }
}

// ---------------- GEMM with bf16 output (+optional fp32 bias on n), vectorized stores ----
template<int AT, int BT>
__global__ __launch_bounds__(256) void k_gemm_bf16(
    const bf16_t* __restrict__ A, long lda, long sAz,
    const bf16_t* __restrict__ Bt, long ldb, long sBz,
    bf16_t* __restrict__ C, long ldc, long sCz,
    const float* __restrict__ bias, int K) {
  __shared__ bf16_t sa[BM * BK];
  __shared__ bf16_t sb[BN * BK];
  long n0 = (long)blockIdx.x * BN;
  long m0 = (long)blockIdx.y * BM;
  long z  = blockIdx.z;
  const bf16_t* Az = A + z * sAz;
  const bf16_t* Bz = Bt + z * sBz;
  bf16_t* Cz = C + z * sCz;
  f32x4 acc[4][4];
  #pragma unroll
  for (int i = 0; i < 4; ++i)
    #pragma unroll
    for (int j = 0; j < 4; ++j) acc[i][j] = (f32x4){0.f, 0.f, 0.f, 0.f};
  gemm_tile<AT, BT>(Az, lda, Bz, ldb, m0, n0, K, sa, sb, acc);
  const int tid = threadIdx.x, wave = tid >> 6, lane = tid & 63;
  const int quad = lane >> 4, l16 = lane & 15;
  const int wm = (wave & 1) * 64, wn = (wave >> 1) * 64;
  #pragma unroll
  for (int i = 0; i < 4; ++i) {
    long row = m0 + wm + i * 16 + l16;
    #pragma unroll
    for (int j = 0; j < 4; ++j) {
      long col = n0 + wn + j * 16 + quad * 4;
      f32x4 b4 = bias ? *(const f32x4*)(bias + col) : (f32x4){0.f, 0.f, 0.f, 0.f};
      bf16x4 o;
      #pragma unroll
      for (int r = 0; r < 4; ++r) o[r] = (bf16_t)(acc[i][j][r] + b4[r]);
      *(bf16x4*)(Cz + row * ldc + col) = o;
    }
  }
}

// ---------------- GEMM with fp32 output (heads), vectorized f32x4 stores ----------------
__global__ __launch_bounds__(256) void k_gemm_f32(
    const bf16_t* __restrict__ A, long lda, long sAz,
    const bf16_t* __restrict__ Bt, long ldb, long sBz,
    float* __restrict__ C, long ldc, long sCz, int K) {
  __shared__ bf16_t sa[BM * BK];
  __shared__ bf16_t sb[BN * BK];
  long n0 = (long)blockIdx.x * BN;
  long m0 = (long)blockIdx.y * BM;
  long z  = blockIdx.z;
  const bf16_t* Az = A + z * sAz;
  const bf16_t* Bz = Bt + z * sBz;
  float* Cz = C + z * sCz;
  f32x4 acc[4][4];
  #pragma unroll
  for (int i = 0; i < 4; ++i)
    #pragma unroll
    for (int j = 0; j < 4; ++j) acc[i][j] = (f32x4){0.f, 0.f, 0.f, 0.f};
  gemm_tile<0, 0>(Az, lda, Bz, ldb, m0, n0, K, sa, sb, acc);
  const int tid = threadIdx.x, wave = tid >> 6, lane = tid & 63;
  const int quad = lane >> 4, l16 = lane & 15;
  const int wm = (wave & 1) * 64, wn = (wave >> 1) * 64;
  #pragma unroll
  for (int i = 0; i < 4; ++i) {
    long row = m0 + wm + i * 16 + l16;
    #pragma unroll
    for (int j = 0; j < 4; ++j) {
      long col = n0 + wn + j * 16 + quad * 4;
      *(f32x4*)(Cz + row * ldc + col) = acc[i][j];
    }
  }
}

// ---------------- big-tile GEMM for G = q16 @ M : 128x256 block, 64x128 wave tile ------
// XCD swizzle: same-m blocks land on same XCD, n-inner ordering for A-tile L2 reuse.
__global__ __launch_bounds__(256, 2) void k_gemm_big(
    const bf16_t* __restrict__ A, const bf16_t* __restrict__ Bt,
    bf16_t* __restrict__ C) {
  __shared__ bf16_t sa[128 * 32];   // 8 KB
  __shared__ bf16_t sb[256 * 32];   // 16 KB
  const int tid = threadIdx.x, wave = tid >> 6, lane = tid & 63;
  const int quad = lane >> 4, l16 = lane & 15;
  int lin = blockIdx.y * 4 + blockIdx.x;      // grid (4, 512)
  int c = lin & 7, j0 = lin >> 3;             // c ~ XCD id
  long m0 = ((long)c * 64 + (j0 >> 2)) * 128; // XCD c owns m-tiles [64c, 64c+64)
  long n0 = (long)(j0 & 3) * 256;             // n-inner: A-tile reused across 4 n-blocks
  const int wm = (wave & 1) * 64;
  const int wn = (wave >> 1) * 128;
  f32x4 acc[4][8];
  #pragma unroll
  for (int i = 0; i < 4; ++i)
    #pragma unroll
    for (int j = 0; j < 8; ++j) acc[i][j] = (f32x4){0.f, 0.f, 0.f, 0.f};
  for (int kt = 0; kt < 1024; kt += 32) {
    __syncthreads();
    #pragma unroll
    for (int r = 0; r < 2; ++r) {
      int L = r * 256 + tid;
      gll16(A + (m0 + (L >> 2)) * 1024 + kt + (L & 3) * 8, sa + (long)(r * 256 + wave * 64) * 8);
    }
    #pragma unroll
    for (int r = 0; r < 4; ++r) {
      int L = r * 256 + tid;
      gll16(Bt + (n0 + (L >> 2)) * 1024 + kt + (L & 3) * 8, sb + (long)(r * 256 + wave * 64) * 8);
    }
    __syncthreads();
    bf16x8 af[4], bfr[8];
    #pragma unroll
    for (int i = 0; i < 4; ++i)
      af[i] = *(const bf16x8*)(sa + (wm + i * 16 + l16) * 32 + quad * 8);
    #pragma unroll
    for (int j = 0; j < 8; ++j)
      bfr[j] = *(const bf16x8*)(sb + (wn + j * 16 + l16) * 32 + quad * 8);
    #pragma unroll
    for (int i = 0; i < 4; ++i)
      #pragma unroll
      for (int j = 0; j < 8; ++j)
        acc[i][j] = __builtin_amdgcn_mfma_f32_16x16x32_bf16(bfr[j], af[i], acc[i][j], 0, 0, 0);
  }
  #pragma unroll
  for (int i = 0; i < 4; ++i) {
    long row = m0 + wm + i * 16 + l16;
    #pragma unroll
    for (int j = 0; j < 8; ++j) {
      long col = n0 + wn + j * 16 + quad * 4;
      bf16x4 o;
      #pragma unroll
      for (int r = 0; r < 4; ++r) o[r] = (bf16_t)(acc[i][j][r]);
      *(bf16x4*)(C + row * 1024 + col) = o;
    }
  }
}

// ---------------- classifier GEMM with XCD swizzle + vectorized epilogue ----------------
__global__ __launch_bounds__(256) void k_gemm_cls(
    const bf16_t* __restrict__ q16, const bf16_t* __restrict__ w1,
    const float* __restrict__ b1, const float* __restrict__ w2,
    float* __restrict__ dsum) {
  __shared__ bf16_t sa[BM * BK];
  __shared__ bf16_t sb[BN * BK];
  // grid (4,16,32): swizzle so the 4 n-blocks of one (s,m) share an XCD
  int lin = ((int)blockIdx.z * 16 + blockIdx.y) * 4 + blockIdx.x;
  int c = lin & 7, j0 = lin >> 3;
  int p = c + 8 * (j0 >> 2);
  long n0 = (long)(j0 & 3) * BN;
  int s = p >> 4;
  long m0 = (long)(p & 15) * BM;
  const bf16_t* A  = q16 + (long)s * Ddim;
  const bf16_t* Bt = w1 + (long)s * Hdim * Ddim;
  f32x4 acc[4][4];
  #pragma unroll
  for (int i = 0; i < 4; ++i)
    #pragma unroll
    for (int j = 0; j < 4; ++j) acc[i][j] = (f32x4){0.f, 0.f, 0.f, 0.f};
  gemm_tile<0, 0>(A, (long)Sdim * Ddim, Bt, Ddim, m0, n0, Ddim, sa, sb, acc);
  const int tid = threadIdx.x, wave = tid >> 6, lane = tid & 63;
  const int quad = lane >> 4, l16 = lane & 15;
  const int wm = (wave & 1) * 64, wn = (wave >> 1) * 64;
  const float* b1s = b1 + (long)s * Hdim;
  const float* w2s = w2 + (long)s * Hdim;
  #pragma unroll
  for (int i = 0; i < 4; ++i) {
    float vsum = 0.f;
    #pragma unroll
    for (int j = 0; j < 4; ++j) {
      long col = n0 + wn + j * 16 + quad * 4;
      f32x4 b4 = *(const f32x4*)(b1s + col);
      f32x4 w4 = *(const f32x4*)(w2s + col);
      #pragma unroll
      for (int r = 0; r < 4; ++r)
        vsum += fmaxf(acc[i][j][r] + b4[r], 0.f) * w4[r];
    }
    vsum += __shfl_xor(vsum, 16);
    vsum += __shfl_xor(vsum, 32);
    if (lane < 16) {
      long row = m0 + wm + i * 16 + l16;
      atomicAdd(&dsum[row * Sdim + s], vsum);
    }
  }
}

// ---------------- d finalize: relu + two 16-way softmaxes ----------------
__global__ void k_finalize_d(const float* __restrict__ dsum, const float* __restrict__ cb2,
                             float* __restrict__ daws, float* __restrict__ out_da,
                             float* __restrict__ out_dv) {
  int t = blockIdx.x * 256 + threadIdx.x;   // over B*S
  int b = t >> 5, s = t & 31;
  float v = fmaxf(dsum[t] + cb2[s], 0.f);
  float m = v;
  #pragma unroll
  for (int mask = 1; mask < 16; mask <<= 1) m = fmaxf(m, __shfl_xor(m, mask));
  float e = __expf(v - m);
  float sum = e;
  #pragma unroll
  for (int mask = 1; mask < 16; mask <<= 1) sum += __shfl_xor(sum, mask);
  float r = e / sum;
  daws[t] = r;
  if (s < 16) out_da[b * 16 + s] = r;
  else        out_dv[b * 16 + (s - 16)] = r;
}

// ---------------- per-batch: scores -> softmax -> pool weights -> pooled vectors --------
#define QPAD 264
__global__ __launch_bounds__(256) void k_attn_pool(
    const bf16_t* __restrict__ q16, const bf16_t* __restrict__ G16,
    const float* __restrict__ daws, const float* __restrict__ u,
    const float* __restrict__ wv, const float* __restrict__ c0p,
    bf16_t* __restrict__ pooled) {
  __shared__ bf16_t qc[32 * QPAD];
  __shared__ bf16_t gc[32 * QPAD];
  __shared__ float sc[32][33];
  __shared__ float qup[32][8], qwp[32][8];
  __shared__ float quL[32], qwL[32], caL[32], cvL[32], daL[16], dvL[16];
  const int tid = threadIdx.x, wave = tid >> 6, lane = tid & 63;
  const int quad = lane >> 4, l16 = lane & 15;
  const long b = blockIdx.x;
  const bf16_t* qb = q16 + b * (Sdim * Ddim);
  const bf16_t* gb = G16 + b * (Sdim * Ddim);
  if (tid < 32) {
    float dval = daws[b * Sdim + tid];
    if (tid < 16) daL[tid] = dval; else dvL[tid - 16] = dval;
  }
  qup[tid >> 3][tid & 7] = 0.f;
  qwp[tid >> 3][tid & 7] = 0.f;
  const int ti = wave & 1, tj = wave >> 1;
  f32x4 acc = (f32x4){0.f, 0.f, 0.f, 0.f};
  for (int kc = 0; kc < Ddim; kc += 256) {
    __syncthreads();
    #pragma unroll
    for (int r = 0; r < 4; ++r) {
      int L = r * 256 + tid;
      int row = L >> 5, koff = (L & 31) * 8;
      *(bf16x8*)(qc + row * QPAD + koff) = *(const bf16x8*)(qb + (long)row * Ddim + kc + koff);
      *(bf16x8*)(gc + row * QPAD + koff) = *(const bf16x8*)(gb + (long)row * Ddim + kc + koff);
    }
    __syncthreads();
    #pragma unroll
    for (int kk = 0; kk < 8; ++kk) {
      bf16x8 a  = *(const bf16x8*)(gc + (ti * 16 + l16) * QPAD + kk * 32 + quad * 8);
      bf16x8 bb = *(const bf16x8*)(qc + (tj * 16 + l16) * QPAD + kk * 32 + quad * 8);
      acc = __builtin_amdgcn_mfma_f32_16x16x32_bf16(a, bb, acc, 0, 0, 0);
    }
    {
      int s2 = tid & 31, sl = tid >> 5;
      float pu = 0.f, pw = 0.f;
      const bf16_t* qrow = qc + s2 * QPAD + sl * 32;
      for (int k = 0; k < 32; ++k) {
        float qv = (float)qrow[k];
        pu += qv * u[kc + sl * 32 + k];
        pw += qv * wv[kc + sl * 32 + k];
      }
      qup[s2][sl] += pu;
      qwp[s2][sl] += pw;
    }
  }
  __syncthreads();
  if (tid < 32) {
    float a0 = 0.f, a1 = 0.f;
    for (int k = 0; k < 8; ++k) { a0 += qup[tid][k]; a1 += qwp[tid][k]; }
    quL[tid] = a0; qwL[tid] = a1;
  }
  __syncthreads();
  {
    float c00 = c0p[0];
    int col = tj * 16 + l16;
    #pragma unroll
    for (int r = 0; r < 4; ++r) {
      int row = ti * 16 + quad * 4 + r;
      sc[row][col] = (acc[r] + quL[row] + qwL[col] + c00) * 0.03125f;
    }
  }
  __syncthreads();
  if (tid < 32) {
    float mx = -1e30f;
    for (int t = 0; t < 32; ++t) mx = fmaxf(mx, sc[tid][t]);
    float sum = 0.f;
    for (int t = 0; t < 32; ++t) { float e = __expf(sc[tid][t] - mx); sc[tid][t] = e; sum += e; }
    float inv = 1.f / sum;
    for (int t = 0; t < 32; ++t) sc[tid][t] *= inv;
  }
  __syncthreads();
  if (tid < 32) {
    float a0 = 0.f, a1 = 0.f;
    for (int s2 = 0; s2 < 16; ++s2) a0 += daL[s2] * sc[s2][tid];
    for (int s2 = 0; s2 < 16; ++s2) a1 += dvL[s2] * sc[16 + s2][tid];
    caL[tid] = a0; cvL[tid] = a1;
  }
  __syncthreads();
  {
    int d0 = tid * 4;
    float ap[4] = {0.f, 0.f, 0.f, 0.f}, vp[4] = {0.f, 0.f, 0.f, 0.f};
    for (int t = 0; t < 32; ++t) {
      float ca = caL[t], cv = cvL[t];
      bf16x4 qv = *(const bf16x4*)(qb + (long)t * Ddim + d0);
      #pragma unroll
      for (int e = 0; e < 4; ++e) {
        float x = (float)qv[e];
        ap[e] += ca * x;
        vp[e] += cv * x;
      }
    }
    bf16x4 pf, pa, pv;
    #pragma unroll
    for (int e = 0; e < 4; ++e) {
      pf[e] = (bf16_t)(0.5f * (ap[e] + vp[e]));
      pa[e] = (bf16_t)ap[e];
      pv[e] = (bf16_t)vp[e];
    }
    *(bf16x4*)(pooled + b * 3072 + d0)        = pf;
    *(bf16x4*)(pooled + b * 3072 + 1024 + d0) = pa;
    *(bf16x4*)(pooled + b * 3072 + 2048 + d0) = pv;
  }
}

// ---------------- LayerNorm + ReLU over F=512 (one wave per row) ----------------
__global__ __launch_bounds__(256) void k_ln(
    const float* __restrict__ Y,
    const float* __restrict__ fb, const float* __restrict__ fg, const float* __restrict__ fbe,
    const float* __restrict__ ab, const float* __restrict__ ag, const float* __restrict__ abe,
    const float* __restrict__ vb, const float* __restrict__ vg, const float* __restrict__ vbe,
    float* __restrict__ out) {
  int wave = threadIdx.x >> 6, lane = threadIdx.x & 63;
  long row = (long)blockIdx.x * 4 + wave;        // [0, 3*B)
  int head = (int)(row >> 11);
  const float* bb = (head == 0) ? fb : (head == 1) ? ab : vb;
  const float* gg = (head == 0) ? fg : (head == 1) ? ag : vg;
  const float* be = (head == 0) ? fbe : (head == 1) ? abe : vbe;
  const float* y = Y + row * Fdim + lane * 8;
  float v[8];
  float s = 0.f;
  #pragma unroll
  for (int k = 0; k < 8; ++k) { v[k] = y[k] + bb[lane * 8 + k]; s += v[k]; }
  #pragma unroll
  for (int m = 1; m < 64; m <<= 1) s += __shfl_xor(s, m);
  float mu = s * (1.f / Fdim);
  float vs = 0.f;
  #pragma unroll
  for (int k = 0; k < 8; ++k) { float t = v[k] - mu; vs += t * t; }
  #pragma unroll
  for (int m = 1; m < 64; m <<= 1) vs += __shfl_xor(vs, m);
  float inv = rsqrtf(vs * (1.f / Fdim) + 1e-5f);
  float* o = out + row * Fdim + lane * 8;
  #pragma unroll
  for (int k = 0; k < 8; ++k) {
    float t = (v[k] - mu) * inv * gg[lane * 8 + k] + be[lane * 8 + k];
    o[k] = fmaxf(t, 0.f);
  }
}

// ---------------- launch ----------------
extern "C" void kernel_launch(void* const* d_in, const int* in_sizes, int n_in,
                              void* d_out, int out_size, void* d_ws, size_t ws_size,
                              hipStream_t stream) {
  const float* q    = (const float*)d_in[0];
  const float* ipw  = (const float*)d_in[1];
  const float* ipb  = (const float*)d_in[2];
  const float* ow   = (const float*)d_in[3];
  const float* ob   = (const float*)d_in[4];
  const float* cw1  = (const float*)d_in[5];
  const float* cb1  = (const float*)d_in[6];
  const float* cw2  = (const float*)d_in[7];
  const float* cb2  = (const float*)d_in[8];
  const float* fusw = (const float*)d_in[9];
  const float* fusb = (const float*)d_in[10];
  const float* fusg = (const float*)d_in[11];
  const float* fusbe= (const float*)d_in[12];
  const float* paw  = (const float*)d_in[13];
  const float* pab  = (const float*)d_in[14];
  const float* pag  = (const float*)d_in[15];
  const float* pabe = (const float*)d_in[16];
  const float* pvw  = (const float*)d_in[17];
  const float* pvb  = (const float*)d_in[18];
  const float* pvg  = (const float*)d_in[19];
  const float* pvbe = (const float*)d_in[20];
  float* out = (float*)d_out;

  // workspace layout (bytes)
  const size_t o_q16   = 0;                    // 134217728
  const size_t o_w16   = 134217728;            // 6291456 (Wq,Wk,Wv)
  const size_t o_ow16  = 140509184;            // 2097152
  const size_t o_cls16 = 142606336;            // 33554432
  const size_t o_hw16  = 176160768;            // 3145728 (fus,pa,pv)
  const size_t o_Mt    = 179306496;            // 2097152
  const size_t o_Nt    = 181403648;            // 2097152
  const size_t o_G16   = 183500800;            // 134217728 (aliased later by S1,Y)
  const size_t o_pool  = 317718528;            // 12582912
  const size_t o_u     = 330301440;            // 4096
  const size_t o_wv    = 330305536;            // 4096
  const size_t o_bp    = 330309632;            // 4096
  const size_t o_c0    = 330313728;            // 256
  const size_t o_dsum  = 330313984;            // 262144
  const size_t o_daws  = 330576128;            // 262144
  const size_t total   = 330838272;
  if (ws_size < total) return;

  char* ws = (char*)d_ws;
  bf16_t* q16   = (bf16_t*)(ws + o_q16);
  bf16_t* w16   = (bf16_t*)(ws + o_w16);
  bf16_t* Wq16  = w16;
  bf16_t* Wk16  = w16 + 1048576;
  bf16_t* Wv16  = w16 + 2097152;
  bf16_t* ow16  = (bf16_t*)(ws + o_ow16);
  bf16_t* cls16 = (bf16_t*)(ws + o_cls16);
  bf16_t* hw16  = (bf16_t*)(ws + o_hw16);
  bf16_t* Mt    = (bf16_t*)(ws + o_Mt);
  bf16_t* Nt    = (bf16_t*)(ws + o_Nt);
  bf16_t* G16   = (bf16_t*)(ws + o_G16);
  bf16_t* S116  = (bf16_t*)(ws + o_G16);                 // alias (G16 dead by then)
  float*  Yf    = (float*)(ws + o_G16 + 12582912);       // alias
  bf16_t* pool16= (bf16_t*)(ws + o_pool);
  float*  uf    = (float*)(ws + o_u);
  float*  wvf   = (float*)(ws + o_wv);
  float*  bpf   = (float*)(ws + o_bp);
  float*  c0f   = (float*)(ws + o_c0);
  float*  dsum  = (float*)(ws + o_dsum);
  float*  daws  = (float*)(ws + o_daws);

  // 1) one fused convert for everything (22413312 float4 elements total)
  k_cvt_all<<<dim3(87552), dim3(256), 0, stream>>>(
      q, ipw, ow, cw1, fusw, paw, pvw, q16, w16, ow16, cls16, hw16);

  // 2) bias precompute
  k_bias_pre<<<dim3(137), dim3(256), 0, stream>>>(ipw, ipb, ow, ob, uf, wvf, bpf, c0f);

  // 3) M^T = Wk^T Wq
  k_gemm_bf16<1, 1><<<dim3(8, 8, 1), dim3(256), 0, stream>>>(
      Wk16, Ddim, 0, Wq16, Ddim, 0, Mt, Ddim, 0, nullptr, Ddim);

  // 4) N^T = Wo @ Wv
  k_gemm_bf16<0, 1><<<dim3(8, 8, 1), dim3(256), 0, stream>>>(
      ow16, Ddim, 0, Wv16, Ddim, 0, Nt, Ddim, 0, nullptr, Ddim);

  // 5) G = q16 @ M   (big-tile kernel, XCD-swizzled)
  k_gemm_big<<<dim3(4, 512), dim3(256), 0, stream>>>(q16, Mt, G16);

  // 6) classifier
  hipMemsetAsync(dsum, 0, (size_t)Bdim * Sdim * sizeof(float), stream);
  k_gemm_cls<<<dim3(4, 16, 32), dim3(256), 0, stream>>>(q16, cls16, cb1, cw2, dsum);

  // 7) d -> softmaxes -> d_a,d_v
  k_finalize_d<<<dim3(256), dim3(256), 0, stream>>>(
      dsum, cb2, daws, out + 3145728, out + 3145728 + 32768);

  // 8) per-batch attention scores + pooling
  k_attn_pool<<<dim3(2048), dim3(256), 0, stream>>>(q16, G16, daws, uf, wvf, c0f, pool16);

  // 9) S1 = pooled @ N + b'
  k_gemm_bf16<0, 0><<<dim3(8, 48, 1), dim3(256), 0, stream>>>(
      pool16, Ddim, 0, Nt, Ddim, 0, S116, Ddim, 0, bpf, Ddim);

  // 10) heads: Y[z] = S1[:,z,:] @ headw[z]^T
  k_gemm_f32<<<dim3(4, 16, 3), dim3(256), 0, stream>>>(
      S116, 3L * Ddim, Ddim, hw16, Ddim, (long)Fdim * Ddim,
      Yf, Fdim, (long)Bdim * Fdim, Ddim);

  // 11) LN + ReLU -> out
  k_ln<<<dim3(1536), dim3(256), 0, stream>>>(
      Yf, fusb, fusg, fusbe, pab, pag, pabe, pvb, pvg, pvbe, out);
}

// Round 3
// 1030.953 us; speedup vs baseline: 1.0949x; 1.0264x over previous
//
#include <hip/hip_runtime.h>

// Problem constants
#define Bdim 2048
#define Sdim 32
#define Ddim 1024
#define Fdim 512
#define Hdim 512

typedef __bf16 bf16_t;
typedef __bf16 bf16x8 __attribute__((ext_vector_type(8)));
typedef __bf16 bf16x4 __attribute__((ext_vector_type(4)));
typedef float  f32x4  __attribute__((ext_vector_type(4)));

#define BM 128
#define BN 128
#define BK 32

// ---------------- async global->LDS, 16B per lane ----------------
__device__ __forceinline__ void gll16(const bf16_t* g, bf16_t* l) {
  __builtin_amdgcn_global_load_lds((const __attribute__((address_space(1))) void*)g,
                                   (__attribute__((address_space(3))) void*)l,
                                   16, 0, 0);
}

// XOR-swizzled LDS offset for BK=32 tiles: slot (row, k-chunk c) holds global chunk
// c ^ ((row>>1)&3). Staging stays lane-contiguous (global_load_lds compatible) and
// fully coalesced; fragment reads spread across all 8 bank groups (2-way = free).
__device__ __forceinline__ int swz32(int row, int k) {
  return row * 32 + (((((k >> 3) ^ ((row >> 1) & 3))) << 3) | (k & 7));
}

// ---------------- fused fp32 -> bf16 convert for ALL weight/input tensors ----------------
__global__ void k_cvt_all(const float* __restrict__ q, const float* __restrict__ ipw,
                          const float* __restrict__ ow, const float* __restrict__ cw1,
                          const float* __restrict__ fusw, const float* __restrict__ paw,
                          const float* __restrict__ pvw,
                          bf16_t* __restrict__ q16, bf16_t* __restrict__ w16,
                          bf16_t* __restrict__ ow16, bf16_t* __restrict__ cls16,
                          bf16_t* __restrict__ hw16) {
  long v = (long)blockIdx.x * 256 + threadIdx.x;
  const float* s; bf16_t* d; long off;
  if (v < 16777216L)      { s = q;    d = q16;            off = 0; }
  else if (v < 17563648L) { s = ipw;  d = w16;            off = 16777216L; }
  else if (v < 17825792L) { s = ow;   d = ow16;           off = 17563648L; }
  else if (v < 22020096L) { s = cw1;  d = cls16;          off = 17825792L; }
  else if (v < 22151168L) { s = fusw; d = hw16;           off = 22020096L; }
  else if (v < 22282240L) { s = paw;  d = hw16 + 524288;  off = 22151168L; }
  else                    { s = pvw;  d = hw16 + 1048576; off = 22282240L; }
  long i = (v - off) * 4;
  float4 t = *(const float4*)(s + i);
  bf16x4 o;
  o[0] = (bf16_t)t.x; o[1] = (bf16_t)t.y; o[2] = (bf16_t)t.z; o[3] = (bf16_t)t.w;
  *(bf16x4*)(d + i) = o;
}

// ---------------- bias precompute: u = Wq^T bk, w = Wk^T bq, b' = Wo bv + out_b, c0 = bq.bk
__global__ void k_bias_pre(const float* __restrict__ ipw, const float* __restrict__ ipb,
                           const float* __restrict__ ow, const float* __restrict__ ob,
                           float* __restrict__ u, float* __restrict__ w,
                           float* __restrict__ bp, float* __restrict__ c0) {
  int blk = blockIdx.x, tid = threadIdx.x;
  if (blk < 4) {
    int d = blk * 256 + tid;
    float acc = 0.f;
    #pragma unroll 8
    for (int e = 0; e < Ddim; ++e) acc += ipw[(long)e * Ddim + d] * ipb[Ddim + e];
    u[d] = acc;
  } else if (blk < 8) {
    int d = (blk - 4) * 256 + tid;
    float acc = 0.f;
    #pragma unroll 8
    for (int e = 0; e < Ddim; ++e) acc += ipw[(long)(Ddim + e) * Ddim + d] * ipb[e];
    w[d] = acc;
  } else if (blk < 136) {
    int o = (blk - 8) * 8 + (tid >> 5);
    int l = tid & 31;
    float acc = 0.f;
    #pragma unroll 4
    for (int e = l; e < Ddim; e += 32) acc += ow[(long)o * Ddim + e] * ipb[2 * Ddim + e];
    #pragma unroll
    for (int m = 1; m < 32; m <<= 1) acc += __shfl_xor(acc, m);
    if (l == 0) bp[o] = acc + ob[o];
  } else {
    __shared__ float red[256];
    float acc = 0.f;
    for (int e = tid; e < Ddim; e += 256) acc += ipb[e] * ipb[Ddim + e];
    red[tid] = acc;
    __syncthreads();
    for (int off = 128; off; off >>= 1) {
      if (tid < off) red[tid] += red[tid + off];
      __syncthreads();
    }
    if (tid == 0) c0[0] = red[0];
  }
}

// ---------------- generic 128x128x32 MFMA mainloop (operand-swapped mfma, swizzled LDS) --
// acc[i][j][r] = C[m0+wm+i*16+l16][n0+wn+j*16+quad*4+r]
template<int AT, int BT>
__device__ __forceinline__ void gemm_tile(const bf16_t* __restrict__ A, long lda,
                                          const bf16_t* __restrict__ Bt, long ldb,
                                          long m0, long n0, int K,
                                          bf16_t* sa, bf16_t* sb, f32x4 acc[4][4]) {
  const int tid  = threadIdx.x;
  const int wave = tid >> 6;
  const int lane = tid & 63;
  const int quad = lane >> 4;
  const int l16  = lane & 15;
  const int wm = (wave & 1) * 64;
  const int wn = (wave >> 1) * 64;

  for (int kt = 0; kt < K; kt += BK) {
    __syncthreads();
    if constexpr (AT == 0) {
      #pragma unroll
      for (int r = 0; r < 2; ++r) {
        int L = r * 256 + tid;
        int row = L >> 2, cs = L & 3;
        int csrc = cs ^ ((row >> 1) & 3);
        gll16(A + (m0 + row) * lda + kt + csrc * 8, sa + (long)(r * 256 + wave * 64) * 8);
      }
    } else {
      #pragma unroll
      for (int r = 0; r < 2; ++r) {
        int L = r * 256 + tid;
        int gk = L >> 4, gm = (L & 15) * 8;
        bf16x8 v = *(const bf16x8*)(A + (long)(kt + gk) * lda + m0 + gm);
        #pragma unroll
        for (int j = 0; j < 8; ++j) sa[swz32(gm + j, gk)] = v[j];
      }
    }
    if constexpr (BT == 0) {
      #pragma unroll
      for (int r = 0; r < 2; ++r) {
        int L = r * 256 + tid;
        int row = L >> 2, cs = L & 3;
        int csrc = cs ^ ((row >> 1) & 3);
        gll16(Bt + (n0 + row) * ldb + kt + csrc * 8, sb + (long)(r * 256 + wave * 64) * 8);
      }
    } else {
      #pragma unroll
      for (int r = 0; r < 2; ++r) {
        int L = r * 256 + tid;
        int gk = L >> 4, gn = (L & 15) * 8;
        bf16x8 v = *(const bf16x8*)(Bt + (long)(kt + gk) * ldb + n0 + gn);
        #pragma unroll
        for (int j = 0; j < 8; ++j) sb[swz32(gn + j, gk)] = v[j];
      }
    }
    __syncthreads();
    bf16x8 af[4], bfr[4];
    #pragma unroll
    for (int i = 0; i < 4; ++i) {
      int row = wm + i * 16 + l16;
      af[i] = *(const bf16x8*)(sa + row * 32 + ((quad ^ ((row >> 1) & 3)) << 3));
    }
    #pragma unroll
    for (int j = 0; j < 4; ++j) {
      int row = wn + j * 16 + l16;
      bfr[j] = *(const bf16x8*)(sb + row * 32 + ((quad ^ ((row >> 1) & 3)) << 3));
    }
    #pragma unroll
    for (int i = 0; i < 4; ++i)
      #pragma unroll
      for (int j = 0; j < 4; ++j)
        acc[i][j] = __builtin_amdgcn_mfma_f32_16x16x32_bf16(bfr[j], af[i], acc[i][j], 0, 0, 0);
  }
}

// ---------------- GEMM with bf16 output (+optional fp32 bias on n), vectorized stores ----
template<int AT, int BT>
__global__ __launch_bounds__(256) void k_gemm_bf16(
    const bf16_t* __restrict__ A, long lda, long sAz,
    const bf16_t* __restrict__ Bt, long ldb, long sBz,
    bf16_t* __restrict__ C, long ldc, long sCz,
    const float* __restrict__ bias, int K) {
  __shared__ bf16_t sa[BM * BK];
  __shared__ bf16_t sb[BN * BK];
  long n0 = (long)blockIdx.x * BN;
  long m0 = (long)blockIdx.y * BM;
  long z  = blockIdx.z;
  const bf16_t* Az = A + z * sAz;
  const bf16_t* Bz = Bt + z * sBz;
  bf16_t* Cz = C + z * sCz;
  f32x4 acc[4][4];
  #pragma unroll
  for (int i = 0; i < 4; ++i)
    #pragma unroll
    for (int j = 0; j < 4; ++j) acc[i][j] = (f32x4){0.f, 0.f, 0.f, 0.f};
  gemm_tile<AT, BT>(Az, lda, Bz, ldb, m0, n0, K, sa, sb, acc);
  const int tid = threadIdx.x, wave = tid >> 6, lane = tid & 63;
  const int quad = lane >> 4, l16 = lane & 15;
  const int wm = (wave & 1) * 64, wn = (wave >> 1) * 64;
  #pragma unroll
  for (int i = 0; i < 4; ++i) {
    long row = m0 + wm + i * 16 + l16;
    #pragma unroll
    for (int j = 0; j < 4; ++j) {
      long col = n0 + wn + j * 16 + quad * 4;
      f32x4 b4 = bias ? *(const f32x4*)(bias + col) : (f32x4){0.f, 0.f, 0.f, 0.f};
      bf16x4 o;
      #pragma unroll
      for (int r = 0; r < 4; ++r) o[r] = (bf16_t)(acc[i][j][r] + b4[r]);
      *(bf16x4*)(Cz + row * ldc + col) = o;
    }
  }
}

// ---------------- GEMM with fp32 output (heads), vectorized f32x4 stores ----------------
__global__ __launch_bounds__(256) void k_gemm_f32(
    const bf16_t* __restrict__ A, long lda, long sAz,
    const bf16_t* __restrict__ Bt, long ldb, long sBz,
    float* __restrict__ C, long ldc, long sCz, int K) {
  __shared__ bf16_t sa[BM * BK];
  __shared__ bf16_t sb[BN * BK];
  long n0 = (long)blockIdx.x * BN;
  long m0 = (long)blockIdx.y * BM;
  long z  = blockIdx.z;
  const bf16_t* Az = A + z * sAz;
  const bf16_t* Bz = Bt + z * sBz;
  float* Cz = C + z * sCz;
  f32x4 acc[4][4];
  #pragma unroll
  for (int i = 0; i < 4; ++i)
    #pragma unroll
    for (int j = 0; j < 4; ++j) acc[i][j] = (f32x4){0.f, 0.f, 0.f, 0.f};
  gemm_tile<0, 0>(Az, lda, Bz, ldb, m0, n0, K, sa, sb, acc);
  const int tid = threadIdx.x, wave = tid >> 6, lane = tid & 63;
  const int quad = lane >> 4, l16 = lane & 15;
  const int wm = (wave & 1) * 64, wn = (wave >> 1) * 64;
  #pragma unroll
  for (int i = 0; i < 4; ++i) {
    long row = m0 + wm + i * 16 + l16;
    #pragma unroll
    for (int j = 0; j < 4; ++j) {
      long col = n0 + wn + j * 16 + quad * 4;
      *(f32x4*)(Cz + row * ldc + col) = acc[i][j];
    }
  }
}

// ---------------- big-tile GEMM for G = q16 @ M : 128x256 block, BK=64, swizzled --------
// XCD swizzle: same-m blocks land on same XCD, n-inner ordering for A-tile L2 reuse.
// BK=64 halves the barrier/vmcnt-drain events (the m97-structure ~20% stall).
__global__ __launch_bounds__(256, 2) void k_gemm_big(
    const bf16_t* __restrict__ A, const bf16_t* __restrict__ Bt,
    bf16_t* __restrict__ C) {
  __shared__ bf16_t sa[128 * 64];   // 16 KB
  __shared__ bf16_t sb[256 * 64];   // 32 KB
  const int tid = threadIdx.x, wave = tid >> 6, lane = tid & 63;
  const int quad = lane >> 4, l16 = lane & 15;
  int lin = blockIdx.y * 4 + blockIdx.x;      // grid (4, 512)
  int c = lin & 7, j0 = lin >> 3;             // c ~ XCD id
  long m0 = ((long)c * 64 + (j0 >> 2)) * 128;
  long n0 = (long)(j0 & 3) * 256;
  const int wm = (wave & 1) * 64;
  const int wn = (wave >> 1) * 128;
  f32x4 acc[4][8];
  #pragma unroll
  for (int i = 0; i < 4; ++i)
    #pragma unroll
    for (int j = 0; j < 8; ++j) acc[i][j] = (f32x4){0.f, 0.f, 0.f, 0.f};
  for (int kt = 0; kt < 1024; kt += 64) {
    __syncthreads();
    #pragma unroll
    for (int r = 0; r < 4; ++r) {           // A: 128 rows x 128 B
      int L = r * 256 + tid;
      int row = L >> 3, cs = L & 7;
      int csrc = cs ^ ((row >> 1) & 7);
      gll16(A + (m0 + row) * 1024 + kt + csrc * 8, sa + (long)(r * 256 + wave * 64) * 8);
    }
    #pragma unroll
    for (int r = 0; r < 8; ++r) {           // B: 256 rows x 128 B
      int L = r * 256 + tid;
      int row = L >> 3, cs = L & 7;
      int csrc = cs ^ ((row >> 1) & 7);
      gll16(Bt + (n0 + row) * 1024 + kt + csrc * 8, sb + (long)(r * 256 + wave * 64) * 8);
    }
    __syncthreads();
    #pragma unroll
    for (int h = 0; h < 2; ++h) {           // two k=32 halves; frags loaded per-half
      bf16x8 af[4], bfr[8];
      #pragma unroll
      for (int i = 0; i < 4; ++i) {
        int row = wm + i * 16 + l16;
        int cc = h * 4 + quad;
        af[i] = *(const bf16x8*)(sa + row * 64 + ((cc ^ ((row >> 1) & 7)) << 3));
      }
      #pragma unroll
      for (int j = 0; j < 8; ++j) {
        int row = wn + j * 16 + l16;
        int cc = h * 4 + quad;
        bfr[j] = *(const bf16x8*)(sb + row * 64 + ((cc ^ ((row >> 1) & 7)) << 3));
      }
      #pragma unroll
      for (int i = 0; i < 4; ++i)
        #pragma unroll
        for (int j = 0; j < 8; ++j)
          acc[i][j] = __builtin_amdgcn_mfma_f32_16x16x32_bf16(bfr[j], af[i], acc[i][j], 0, 0, 0);
    }
  }
  #pragma unroll
  for (int i = 0; i < 4; ++i) {
    long row = m0 + wm + i * 16 + l16;
    #pragma unroll
    for (int j = 0; j < 8; ++j) {
      long col = n0 + wn + j * 16 + quad * 4;
      bf16x4 o;
      #pragma unroll
      for (int r = 0; r < 4; ++r) o[r] = (bf16_t)(acc[i][j][r]);
      *(bf16x4*)(C + row * 1024 + col) = o;
    }
  }
}

// ---------------- classifier GEMM with XCD swizzle + vectorized epilogue ----------------
__global__ __launch_bounds__(256) void k_gemm_cls(
    const bf16_t* __restrict__ q16, const bf16_t* __restrict__ w1,
    const float* __restrict__ b1, const float* __restrict__ w2,
    float* __restrict__ dsum) {
  __shared__ bf16_t sa[BM * BK];
  __shared__ bf16_t sb[BN * BK];
  int lin = ((int)blockIdx.z * 16 + blockIdx.y) * 4 + blockIdx.x;
  int c = lin & 7, j0 = lin >> 3;
  int p = c + 8 * (j0 >> 2);
  long n0 = (long)(j0 & 3) * BN;
  int s = p >> 4;
  long m0 = (long)(p & 15) * BM;
  const bf16_t* A  = q16 + (long)s * Ddim;
  const bf16_t* Bt = w1 + (long)s * Hdim * Ddim;
  f32x4 acc[4][4];
  #pragma unroll
  for (int i = 0; i < 4; ++i)
    #pragma unroll
    for (int j = 0; j < 4; ++j) acc[i][j] = (f32x4){0.f, 0.f, 0.f, 0.f};
  gemm_tile<0, 0>(A, (long)Sdim * Ddim, Bt, Ddim, m0, n0, Ddim, sa, sb, acc);
  const int tid = threadIdx.x, wave = tid >> 6, lane = tid & 63;
  const int quad = lane >> 4, l16 = lane & 15;
  const int wm = (wave & 1) * 64, wn = (wave >> 1) * 64;
  const float* b1s = b1 + (long)s * Hdim;
  const float* w2s = w2 + (long)s * Hdim;
  #pragma unroll
  for (int i = 0; i < 4; ++i) {
    float vsum = 0.f;
    #pragma unroll
    for (int j = 0; j < 4; ++j) {
      long col = n0 + wn + j * 16 + quad * 4;
      f32x4 b4 = *(const f32x4*)(b1s + col);
      f32x4 w4 = *(const f32x4*)(w2s + col);
      #pragma unroll
      for (int r = 0; r < 4; ++r)
        vsum += fmaxf(acc[i][j][r] + b4[r], 0.f) * w4[r];
    }
    vsum += __shfl_xor(vsum, 16);
    vsum += __shfl_xor(vsum, 32);
    if (lane < 16) {
      long row = m0 + wm + i * 16 + l16;
      atomicAdd(&dsum[row * Sdim + s], vsum);
    }
  }
}

// ---------------- d finalize: relu + two 16-way softmaxes ----------------
__global__ void k_finalize_d(const float* __restrict__ dsum, const float* __restrict__ cb2,
                             float* __restrict__ daws, float* __restrict__ out_da,
                             float* __restrict__ out_dv) {
  int t = blockIdx.x * 256 + threadIdx.x;   // over B*S
  int b = t >> 5, s = t & 31;
  float v = fmaxf(dsum[t] + cb2[s], 0.f);
  float m = v;
  #pragma unroll
  for (int mask = 1; mask < 16; mask <<= 1) m = fmaxf(m, __shfl_xor(m, mask));
  float e = __expf(v - m);
  float sum = e;
  #pragma unroll
  for (int mask = 1; mask < 16; mask <<= 1) sum += __shfl_xor(sum, mask);
  float r = e / sum;
  daws[t] = r;
  if (s < 16) out_da[b * 16 + s] = r;
  else        out_dv[b * 16 + (s - 16)] = r;
}

// ---------------- per-batch: scores -> softmax -> pool weights -> pooled vectors --------
#define QPAD 264
__global__ __launch_bounds__(256) void k_attn_pool(
    const bf16_t* __restrict__ q16, const bf16_t* __restrict__ G16,
    const float* __restrict__ daws, const float* __restrict__ u,
    const float* __restrict__ wv, const float* __restrict__ c0p,
    bf16_t* __restrict__ pooled) {
  __shared__ bf16_t qc[32 * QPAD];
  __shared__ bf16_t gc[32 * QPAD];
  __shared__ float sc[32][33];
  __shared__ float qup[32][8], qwp[32][8];
  __shared__ float quL[32], qwL[32], caL[32], cvL[32], daL[16], dvL[16];
  const int tid = threadIdx.x, wave = tid >> 6, lane = tid & 63;
  const int quad = lane >> 4, l16 = lane & 15;
  const long b = blockIdx.x;
  const bf16_t* qb = q16 + b * (Sdim * Ddim);
  const bf16_t* gb = G16 + b * (Sdim * Ddim);
  if (tid < 32) {
    float dval = daws[b * Sdim + tid];
    if (tid < 16) daL[tid] = dval; else dvL[tid - 16] = dval;
  }
  qup[tid >> 3][tid & 7] = 0.f;
  qwp[tid >> 3][tid & 7] = 0.f;
  const int ti = wave & 1, tj = wave >> 1;
  f32x4 acc = (f32x4){0.f, 0.f, 0.f, 0.f};
  for (int kc = 0; kc < Ddim; kc += 256) {
    __syncthreads();
    #pragma unroll
    for (int r = 0; r < 4; ++r) {
      int L = r * 256 + tid;
      int row = L >> 5, koff = (L & 31) * 8;
      *(bf16x8*)(qc + row * QPAD + koff) = *(const bf16x8*)(qb + (long)row * Ddim + kc + koff);
      *(bf16x8*)(gc + row * QPAD + koff) = *(const bf16x8*)(gb + (long)row * Ddim + kc + koff);
    }
    __syncthreads();
    #pragma unroll
    for (int kk = 0; kk < 8; ++kk) {
      bf16x8 a  = *(const bf16x8*)(gc + (ti * 16 + l16) * QPAD + kk * 32 + quad * 8);
      bf16x8 bb = *(const bf16x8*)(qc + (tj * 16 + l16) * QPAD + kk * 32 + quad * 8);
      acc = __builtin_amdgcn_mfma_f32_16x16x32_bf16(a, bb, acc, 0, 0, 0);
    }
    {
      int s2 = tid & 31, sl = tid >> 5;
      float pu = 0.f, pw = 0.f;
      const bf16_t* qrow = qc + s2 * QPAD + sl * 32;
      const float* ub = u + kc + sl * 32;
      const float* wb = wv + kc + sl * 32;
      #pragma unroll
      for (int kb = 0; kb < 4; ++kb) {
        bf16x8 qv = *(const bf16x8*)(qrow + kb * 8);
        f32x4 u0 = *(const f32x4*)(ub + kb * 8);
        f32x4 u1 = *(const f32x4*)(ub + kb * 8 + 4);
        f32x4 w0 = *(const f32x4*)(wb + kb * 8);
        f32x4 w1 = *(const f32x4*)(wb + kb * 8 + 4);
        #pragma unroll
        for (int e = 0; e < 4; ++e) {
          pu += (float)qv[e] * u0[e] + (float)qv[e + 4] * u1[e];
          pw += (float)qv[e] * w0[e] + (float)qv[e + 4] * w1[e];
        }
      }
      qup[s2][sl] += pu;
      qwp[s2][sl] += pw;
    }
  }
  __syncthreads();
  if (tid < 32) {
    float a0 = 0.f, a1 = 0.f;
    for (int k = 0; k < 8; ++k) { a0 += qup[tid][k]; a1 += qwp[tid][k]; }
    quL[tid] = a0; qwL[tid] = a1;
  }
  __syncthreads();
  {
    float c00 = c0p[0];
    int col = tj * 16 + l16;
    #pragma unroll
    for (int r = 0; r < 4; ++r) {
      int row = ti * 16 + quad * 4 + r;
      sc[row][col] = (acc[r] + quL[row] + qwL[col] + c00) * 0.03125f;
    }
  }
  __syncthreads();
  if (tid < 32) {
    float mx = -1e30f;
    for (int t = 0; t < 32; ++t) mx = fmaxf(mx, sc[tid][t]);
    float sum = 0.f;
    for (int t = 0; t < 32; ++t) { float e = __expf(sc[tid][t] - mx); sc[tid][t] = e; sum += e; }
    float inv = 1.f / sum;
    for (int t = 0; t < 32; ++t) sc[tid][t] *= inv;
  }
  __syncthreads();
  if (tid < 32) {
    float a0 = 0.f, a1 = 0.f;
    for (int s2 = 0; s2 < 16; ++s2) a0 += daL[s2] * sc[s2][tid];
    for (int s2 = 0; s2 < 16; ++s2) a1 += dvL[s2] * sc[16 + s2][tid];
    caL[tid] = a0; cvL[tid] = a1;
  }
  __syncthreads();
  {
    int d0 = tid * 4;
    float ap[4] = {0.f, 0.f, 0.f, 0.f}, vp[4] = {0.f, 0.f, 0.f, 0.f};
    for (int t = 0; t < 32; ++t) {
      float ca = caL[t], cv = cvL[t];
      bf16x4 qv = *(const bf16x4*)(qb + (long)t * Ddim + d0);
      #pragma unroll
      for (int e = 0; e < 4; ++e) {
        float x = (float)qv[e];
        ap[e] += ca * x;
        vp[e] += cv * x;
      }
    }
    bf16x4 pf, pa, pv;
    #pragma unroll
    for (int e = 0; e < 4; ++e) {
      pf[e] = (bf16_t)(0.5f * (ap[e] + vp[e]));
      pa[e] = (bf16_t)ap[e];
      pv[e] = (bf16_t)vp[e];
    }
    *(bf16x4*)(pooled + b * 3072 + d0)        = pf;
    *(bf16x4*)(pooled + b * 3072 + 1024 + d0) = pa;
    *(bf16x4*)(pooled + b * 3072 + 2048 + d0) = pv;
  }
}

// ---------------- LayerNorm + ReLU over F=512 (one wave per row) ----------------
__global__ __launch_bounds__(256) void k_ln(
    const float* __restrict__ Y,
    const float* __restrict__ fb, const float* __restrict__ fg, const float* __restrict__ fbe,
    const float* __restrict__ ab, const float* __restrict__ ag, const float* __restrict__ abe,
    const float* __restrict__ vb, const float* __restrict__ vg, const float* __restrict__ vbe,
    float* __restrict__ out) {
  int wave = threadIdx.x >> 6, lane = threadIdx.x & 63;
  long row = (long)blockIdx.x * 4 + wave;        // [0, 3*B)
  int head = (int)(row >> 11);
  const float* bb = (head == 0) ? fb : (head == 1) ? ab : vb;
  const float* gg = (head == 0) ? fg : (head == 1) ? ag : vg;
  const float* be = (head == 0) ? fbe : (head == 1) ? abe : vbe;
  const float* y = Y + row * Fdim + lane * 8;
  float v[8];
  float s = 0.f;
  #pragma unroll
  for (int k = 0; k < 8; ++k) { v[k] = y[k] + bb[lane * 8 + k]; s += v[k]; }
  #pragma unroll
  for (int m = 1; m < 64; m <<= 1) s += __shfl_xor(s, m);
  float mu = s * (1.f / Fdim);
  float vs = 0.f;
  #pragma unroll
  for (int k = 0; k < 8; ++k) { float t = v[k] - mu; vs += t * t; }
  #pragma unroll
  for (int m = 1; m < 64; m <<= 1) vs += __shfl_xor(vs, m);
  float inv = rsqrtf(vs * (1.f / Fdim) + 1e-5f);
  float* o = out + row * Fdim + lane * 8;
  #pragma unroll
  for (int k = 0; k < 8; ++k) {
    float t = (v[k] - mu) * inv * gg[lane * 8 + k] + be[lane * 8 + k];
    o[k] = fmaxf(t, 0.f);
  }
}

// ---------------- launch ----------------
extern "C" void kernel_launch(void* const* d_in, const int* in_sizes, int n_in,
                              void* d_out, int out_size, void* d_ws, size_t ws_size,
                              hipStream_t stream) {
  const float* q    = (const float*)d_in[0];
  const float* ipw  = (const float*)d_in[1];
  const float* ipb  = (const float*)d_in[2];
  const float* ow   = (const float*)d_in[3];
  const float* ob   = (const float*)d_in[4];
  const float* cw1  = (const float*)d_in[5];
  const float* cb1  = (const float*)d_in[6];
  const float* cw2  = (const float*)d_in[7];
  const float* cb2  = (const float*)d_in[8];
  const float* fusw = (const float*)d_in[9];
  const float* fusb = (const float*)d_in[10];
  const float* fusg = (const float*)d_in[11];
  const float* fusbe= (const float*)d_in[12];
  const float* paw  = (const float*)d_in[13];
  const float* pab  = (const float*)d_in[14];
  const float* pag  = (const float*)d_in[15];
  const float* pabe = (const float*)d_in[16];
  const float* pvw  = (const float*)d_in[17];
  const float* pvb  = (const float*)d_in[18];
  const float* pvg  = (const float*)d_in[19];
  const float* pvbe = (const float*)d_in[20];
  float* out = (float*)d_out;

  // workspace layout (bytes)
  const size_t o_q16   = 0;                    // 134217728
  const size_t o_w16   = 134217728;            // 6291456 (Wq,Wk,Wv)
  const size_t o_ow16  = 140509184;            // 2097152
  const size_t o_cls16 = 142606336;            // 33554432
  const size_t o_hw16  = 176160768;            // 3145728 (fus,pa,pv)
  const size_t o_Mt    = 179306496;            // 2097152
  const size_t o_Nt    = 181403648;            // 2097152
  const size_t o_G16   = 183500800;            // 134217728 (aliased later by S1,Y)
  const size_t o_pool  = 317718528;            // 12582912
  const size_t o_u     = 330301440;            // 4096
  const size_t o_wv    = 330305536;            // 4096
  const size_t o_bp    = 330309632;            // 4096
  const size_t o_c0    = 330313728;            // 256
  const size_t o_dsum  = 330313984;            // 262144
  const size_t o_daws  = 330576128;            // 262144
  const size_t total   = 330838272;
  if (ws_size < total) return;

  char* ws = (char*)d_ws;
  bf16_t* q16   = (bf16_t*)(ws + o_q16);
  bf16_t* w16   = (bf16_t*)(ws + o_w16);
  bf16_t* Wq16  = w16;
  bf16_t* Wk16  = w16 + 1048576;
  bf16_t* Wv16  = w16 + 2097152;
  bf16_t* ow16  = (bf16_t*)(ws + o_ow16);
  bf16_t* cls16 = (bf16_t*)(ws + o_cls16);
  bf16_t* hw16  = (bf16_t*)(ws + o_hw16);
  bf16_t* Mt    = (bf16_t*)(ws + o_Mt);
  bf16_t* Nt    = (bf16_t*)(ws + o_Nt);
  bf16_t* G16   = (bf16_t*)(ws + o_G16);
  bf16_t* S116  = (bf16_t*)(ws + o_G16);                 // alias (G16 dead by then)
  float*  Yf    = (float*)(ws + o_G16 + 12582912);       // alias
  bf16_t* pool16= (bf16_t*)(ws + o_pool);
  float*  uf    = (float*)(ws + o_u);
  float*  wvf   = (float*)(ws + o_wv);
  float*  bpf   = (float*)(ws + o_bp);
  float*  c0f   = (float*)(ws + o_c0);
  float*  dsum  = (float*)(ws + o_dsum);
  float*  daws  = (float*)(ws + o_daws);

  // 1) one fused convert for everything
  k_cvt_all<<<dim3(87552), dim3(256), 0, stream>>>(
      q, ipw, ow, cw1, fusw, paw, pvw, q16, w16, ow16, cls16, hw16);

  // 2) bias precompute
  k_bias_pre<<<dim3(137), dim3(256), 0, stream>>>(ipw, ipb, ow, ob, uf, wvf, bpf, c0f);

  // 3) M^T = Wk^T Wq
  k_gemm_bf16<1, 1><<<dim3(8, 8, 1), dim3(256), 0, stream>>>(
      Wk16, Ddim, 0, Wq16, Ddim, 0, Mt, Ddim, 0, nullptr, Ddim);

  // 4) N^T = Wo @ Wv
  k_gemm_bf16<0, 1><<<dim3(8, 8, 1), dim3(256), 0, stream>>>(
      ow16, Ddim, 0, Wv16, Ddim, 0, Nt, Ddim, 0, nullptr, Ddim);

  // 5) G = q16 @ M   (big-tile kernel, XCD-swizzled, BK=64)
  k_gemm_big<<<dim3(4, 512), dim3(256), 0, stream>>>(q16, Mt, G16);

  // 6) classifier
  hipMemsetAsync(dsum, 0, (size_t)Bdim * Sdim * sizeof(float), stream);
  k_gemm_cls<<<dim3(4, 16, 32), dim3(256), 0, stream>>>(q16, cls16, cb1, cw2, dsum);

  // 7) d -> softmaxes -> d_a,d_v
  k_finalize_d<<<dim3(256), dim3(256), 0, stream>>>(
      dsum, cb2, daws, out + 3145728, out + 3145728 + 32768);

  // 8) per-batch attention scores + pooling
  k_attn_pool<<<dim3(2048), dim3(256), 0, stream>>>(q16, G16, daws, uf, wvf, c0f, pool16);

  // 9) S1 = pooled @ N + b'
  k_gemm_bf16<0, 0><<<dim3(8, 48, 1), dim3(256), 0, stream>>>(
      pool16, Ddim, 0, Nt, Ddim, 0, S116, Ddim, 0, bpf, Ddim);

  // 10) heads: Y[z] = S1[:,z,:] @ headw[z]^T
  k_gemm_f32<<<dim3(4, 16, 3), dim3(256), 0, stream>>>(
      S116, 3L * Ddim, Ddim, hw16, Ddim, (long)Fdim * Ddim,
      Yf, Fdim, (long)Bdim * Fdim, Ddim);

  // 11) LN + ReLU -> out
  k_ln<<<dim3(1536), dim3(256), 0, stream>>>(
      Yf, fusb, fusg, fusbe, pab, pag, pabe, pvb, pvg, pvbe, out);
}